// Round 1
// baseline (7397.372 us; speedup 1.0000x reference)
//
#include <hip/hip_runtime.h>
#include <hip/hip_bf16.h>

#define L_  4
#define D_  1024
#define DK_ 64
#define B_  8
#define S_  512
#define FF_ 4096
#define M_  (B_*S_)      // 4096 rows total
#define EPS_ 1e-3f

// x[b,s,d] = emb[seq[b,s], d] + pes[s, 0]   (positional "bug": scalar per position)
__global__ void embed_kernel(const int* __restrict__ seq, const float* __restrict__ emb,
                             const float* __restrict__ pes, float* __restrict__ x) {
    int idx = blockIdx.x * 256 + threadIdx.x;     // over M_*D_
    int md  = idx >> 10;                          // / D_
    int d   = idx & (D_ - 1);
    int s   = md & (S_ - 1);
    x[idx] = emb[(size_t)seq[md] * D_ + d] + pes[s * D_];
}

// C[M,N] = A[M,K] @ W[K,N] + bias[N], optional ReLU. Tiles 64x64, K-tile 16.
// block(16,16), each thread 4x4 outputs. M,N multiples of 64; K multiple of 16.
template<int RELU>
__global__ void gemm_bias(const float* __restrict__ A, const float* __restrict__ W,
                          const float* __restrict__ bias, float* __restrict__ C,
                          int M, int N, int K) {
    __shared__ float As[16][65];   // [k][m]
    __shared__ float Bs[16][65];   // [k][n]
    const int tx = threadIdx.x, ty = threadIdx.y;
    const int tid = ty * 16 + tx;
    const int m0 = blockIdx.y * 64, n0 = blockIdx.x * 64;
    float acc[4][4] = {};
    for (int k0 = 0; k0 < K; k0 += 16) {
        #pragma unroll
        for (int t = 0; t < 4; t++) {
            int idx = tid + t * 256;            // 0..1023
            int r = idx >> 4, c = idx & 15;     // A tile 64x16
            As[c][r] = A[(size_t)(m0 + r) * K + k0 + c];
            int br = idx >> 6, bc = idx & 63;   // B tile 16x64
            Bs[br][bc] = W[(size_t)(k0 + br) * N + n0 + bc];
        }
        __syncthreads();
        #pragma unroll
        for (int kk = 0; kk < 16; kk++) {
            float a[4], b[4];
            #pragma unroll
            for (int i = 0; i < 4; i++) a[i] = As[kk][ty * 4 + i];
            #pragma unroll
            for (int j = 0; j < 4; j++) b[j] = Bs[kk][tx * 4 + j];
            #pragma unroll
            for (int i = 0; i < 4; i++)
                #pragma unroll
                for (int j = 0; j < 4; j++) acc[i][j] = fmaf(a[i], b[j], acc[i][j]);
        }
        __syncthreads();
    }
    #pragma unroll
    for (int i = 0; i < 4; i++) {
        int m = m0 + ty * 4 + i;
        #pragma unroll
        for (int j = 0; j < 4; j++) {
            int n = n0 + tx * 4 + j;
            float v = acc[i][j] + bias[n];
            if (RELU) v = fmaxf(v, 0.f);
            C[(size_t)m * N + n] = v;
        }
    }
}

// score[b,i,j] = scale * dot(q[b,i,:], k[b,j,:]);  DK=64 fits one LDS tile
__global__ void score_kernel(const float* __restrict__ q, const float* __restrict__ kk,
                             float* __restrict__ sc, float scale) {
    int b = blockIdx.z;
    int i0 = blockIdx.y * 64, j0 = blockIdx.x * 64;
    const float* qb = q  + (size_t)b * S_ * DK_;
    const float* kb = kk + (size_t)b * S_ * DK_;
    __shared__ float Qs[64][65], Ks[64][65];
    const int tid = threadIdx.y * 16 + threadIdx.x;
    #pragma unroll
    for (int t = 0; t < 16; t++) {
        int idx = tid + t * 256;                // 0..4095
        int r = idx >> 6, c = idx & 63;
        Qs[r][c] = qb[(i0 + r) * DK_ + c];
        Ks[r][c] = kb[(j0 + r) * DK_ + c];
    }
    __syncthreads();
    float acc[4][4] = {};
    #pragma unroll 8
    for (int d = 0; d < DK_; d++) {
        float a[4], bb[4];
        #pragma unroll
        for (int i = 0; i < 4; i++) a[i]  = Qs[threadIdx.y * 4 + i][d];
        #pragma unroll
        for (int j = 0; j < 4; j++) bb[j] = Ks[threadIdx.x * 4 + j][d];
        #pragma unroll
        for (int i = 0; i < 4; i++)
            #pragma unroll
            for (int j = 0; j < 4; j++) acc[i][j] = fmaf(a[i], bb[j], acc[i][j]);
    }
    float* sb = sc + (size_t)b * S_ * S_;
    #pragma unroll
    for (int i = 0; i < 4; i++)
        #pragma unroll
        for (int j = 0; j < 4; j++)
            sb[(size_t)(i0 + threadIdx.y * 4 + i) * S_ + j0 + threadIdx.x * 4 + j] = acc[i][j] * scale;
}

// in-place softmax over rows of [B*S, S]; one block (256 thr) per row, S=512
__global__ void softmax_kernel(float* __restrict__ sc) {
    float* p = sc + (size_t)blockIdx.x * S_;
    int tid = threadIdx.x;
    float v0 = p[tid], v1 = p[tid + 256];
    float m = fmaxf(v0, v1);
    #pragma unroll
    for (int off = 32; off > 0; off >>= 1) m = fmaxf(m, __shfl_xor(m, off, 64));
    __shared__ float wmax[4], wsum[4];
    int wid = tid >> 6, lane = tid & 63;
    if (lane == 0) wmax[wid] = m;
    __syncthreads();
    m = fmaxf(fmaxf(wmax[0], wmax[1]), fmaxf(wmax[2], wmax[3]));
    v0 = __expf(v0 - m); v1 = __expf(v1 - m);
    float s = v0 + v1;
    #pragma unroll
    for (int off = 32; off > 0; off >>= 1) s += __shfl_xor(s, off, 64);
    if (lane == 0) wsum[wid] = s;
    __syncthreads();
    float inv = 1.0f / (wsum[0] + wsum[1] + wsum[2] + wsum[3]);
    p[tid] = v0 * inv; p[tid + 256] = v1 * inv;
}

// H[b] = P[b][S,S] @ V[b][S,DK]; tiles 64(rows) x 64(=DK), K-tile 16
__global__ void pv_kernel(const float* __restrict__ P, const float* __restrict__ V,
                          float* __restrict__ H) {
    int b = blockIdx.z;
    const float* Pb = P + (size_t)b * S_ * S_;
    const float* Vb = V + (size_t)b * S_ * DK_;
    float* Hb = H + (size_t)b * S_ * DK_;
    int m0 = blockIdx.y * 64;
    __shared__ float Ps[16][65], Vs[16][65];
    const int tid = threadIdx.y * 16 + threadIdx.x;
    float acc[4][4] = {};
    for (int k0 = 0; k0 < S_; k0 += 16) {
        #pragma unroll
        for (int t = 0; t < 4; t++) {
            int idx = tid + t * 256;
            int r = idx >> 4, c = idx & 15;
            Ps[c][r] = Pb[(size_t)(m0 + r) * S_ + k0 + c];
            int br = idx >> 6, bc = idx & 63;
            Vs[br][bc] = Vb[(k0 + br) * DK_ + bc];
        }
        __syncthreads();
        #pragma unroll
        for (int kk = 0; kk < 16; kk++) {
            float a[4], bb[4];
            #pragma unroll
            for (int i = 0; i < 4; i++) a[i]  = Ps[kk][threadIdx.y * 4 + i];
            #pragma unroll
            for (int j = 0; j < 4; j++) bb[j] = Vs[kk][threadIdx.x * 4 + j];
            #pragma unroll
            for (int i = 0; i < 4; i++)
                #pragma unroll
                for (int j = 0; j < 4; j++) acc[i][j] = fmaf(a[i], bb[j], acc[i][j]);
        }
        __syncthreads();
    }
    #pragma unroll
    for (int i = 0; i < 4; i++)
        #pragma unroll
        for (int j = 0; j < 4; j++)
            Hb[(m0 + threadIdx.y * 4 + i) * DK_ + threadIdx.x * 4 + j] = acc[i][j];
}

// dst = gamma*(x + r - mean)*rsqrt(var+eps) + beta   (elementwise, BN over last axis)
__global__ void bn_residual(const float* __restrict__ x, const float* __restrict__ r,
                            const float* __restrict__ g, const float* __restrict__ b,
                            const float* __restrict__ mu, const float* __restrict__ var,
                            float* __restrict__ dst) {
    int idx = blockIdx.x * 256 + threadIdx.x;     // over M_*D_
    int d = idx & (D_ - 1);
    float s = x[idx] + r[idx];
    dst[idx] = g[d] * (s - mu[d]) * rsqrtf(var[d] + EPS_) + b[d];
}

extern "C" void kernel_launch(void* const* d_in, const int* in_sizes, int n_in,
                              void* d_out, int out_size, void* d_ws, size_t ws_size,
                              hipStream_t stream) {
    const int*   seq = (const int*)  d_in[0];
    const float* emb = (const float*)d_in[1];
    const float* pes = (const float*)d_in[2];
    const float* wq  = (const float*)d_in[3];
    const float* bq  = (const float*)d_in[4];
    const float* wk  = (const float*)d_in[5];
    const float* bk  = (const float*)d_in[6];
    const float* wv  = (const float*)d_in[7];
    const float* bv  = (const float*)d_in[8];
    const float* wo  = (const float*)d_in[9];
    const float* bo  = (const float*)d_in[10];
    const float* ag  = (const float*)d_in[11];
    const float* ab  = (const float*)d_in[12];
    const float* am  = (const float*)d_in[13];
    const float* av  = (const float*)d_in[14];
    const float* w1  = (const float*)d_in[15];
    const float* b1  = (const float*)d_in[16];
    const float* w2  = (const float*)d_in[17];
    const float* b2  = (const float*)d_in[18];
    const float* fg  = (const float*)d_in[19];
    const float* fb  = (const float*)d_in[20];
    const float* fm  = (const float*)d_in[21];
    const float* fv  = (const float*)d_in[22];
    float* out = (float*)d_out;

    // workspace layout (floats): X | q | k | v | score | head | h   (~76 MB)
    float* ws = (float*)d_ws;
    size_t off = 0;
    float* X  = ws + off; off += (size_t)M_ * D_;        // 4M
    float* q  = ws + off; off += (size_t)M_ * DK_;       // 256K
    float* k  = ws + off; off += (size_t)M_ * DK_;
    float* v  = ws + off; off += (size_t)M_ * DK_;
    float* sc = ws + off; off += (size_t)B_ * S_ * S_;   // 2M
    float* hd = ws + off; off += (size_t)M_ * DK_;
    float* h  = ws + off; off += (size_t)M_ * FF_;       // 16M
    float* tmp = out;   // reuse d_out as the attention/FFN projection buffer

    dim3 blk(16, 16);
    const float scale = 0.125f;   // 1/sqrt(64)

    embed_kernel<<<M_ * D_ / 256, 256, 0, stream>>>(seq, emb, pes, X);

    for (int l = 0; l < L_; l++) {
        gemm_bias<0><<<dim3(1, 64), blk, 0, stream>>>(X, wq + (size_t)l * D_ * DK_, bq + l * DK_, q, M_, DK_, D_);
        gemm_bias<0><<<dim3(1, 64), blk, 0, stream>>>(X, wk + (size_t)l * D_ * DK_, bk + l * DK_, k, M_, DK_, D_);
        gemm_bias<0><<<dim3(1, 64), blk, 0, stream>>>(X, wv + (size_t)l * D_ * DK_, bv + l * DK_, v, M_, DK_, D_);

        score_kernel<<<dim3(S_ / 64, S_ / 64, B_), blk, 0, stream>>>(q, k, sc, scale);
        softmax_kernel<<<B_ * S_, 256, 0, stream>>>(sc);
        pv_kernel<<<dim3(1, S_ / 64, B_), blk, 0, stream>>>(sc, v, hd);

        gemm_bias<0><<<dim3(D_ / 64, M_ / 64), blk, 0, stream>>>(hd, wo + (size_t)l * DK_ * D_, bo + l * D_, tmp, M_, D_, DK_);
        bn_residual<<<M_ * D_ / 256, 256, 0, stream>>>(X, tmp, ag + l * D_, ab + l * D_, am + l * D_, av + l * D_, X);

        gemm_bias<1><<<dim3(FF_ / 64, M_ / 64), blk, 0, stream>>>(X, w1 + (size_t)l * D_ * FF_, b1 + l * FF_, h, M_, FF_, D_);
        gemm_bias<0><<<dim3(D_ / 64, M_ / 64), blk, 0, stream>>>(h, w2 + (size_t)l * FF_ * D_, b2 + l * D_, tmp, M_, D_, FF_);
        bn_residual<<<M_ * D_ / 256, 256, 0, stream>>>(X, tmp, fg + l * D_, fb + l * D_, fm + l * D_, fv + l * D_,
                                                       (l == L_ - 1) ? out : X);
    }
}

// Round 2
// 1413.999 us; speedup vs baseline: 5.2315x; 5.2315x over previous
//
#include <hip/hip_runtime.h>
#include <hip/hip_bf16.h>
#include <stdint.h>

#define L_  4
#define D_  1024
#define DK_ 64
#define B_  8
#define S_  512
#define FF_ 4096
#define M_  (B_*S_)      // 4096 rows
#define EPS_ 1e-3f
#define QKVN_ 256        // q|k|v|pad packed width

typedef __bf16 bf16_t;
typedef bf16_t bf16x8 __attribute__((ext_vector_type(8)));
typedef float  f32x4  __attribute__((ext_vector_type(4)));

__device__ __forceinline__ bf16_t f2b(float f) {
    union { float f; uint32_t u; } v; v.f = f;
    uint32_t r = v.u + 0x7fff + ((v.u >> 16) & 1);   // RNE
    uint16_t h = (uint16_t)(r >> 16);
    bf16_t o; __builtin_memcpy(&o, &h, 2); return o;
}

__device__ __forceinline__ void gl2lds16(const bf16_t* g, bf16_t* l) {
    __builtin_amdgcn_global_load_lds(
        (__attribute__((address_space(1))) void*)g,
        (__attribute__((address_space(3))) void*)l, 16, 0, 0);
}

// ---------------- embed: x = emb[seq] + pes[s,0]; also bf16 copy ----------------
__global__ void embed_kernel(const int* __restrict__ seq, const float* __restrict__ emb,
                             const float* __restrict__ pes, float* __restrict__ x,
                             bf16_t* __restrict__ xb) {
    int idx = blockIdx.x * 256 + threadIdx.x;     // over M_*D_
    int md  = idx >> 10;
    int d   = idx & (D_ - 1);
    int s   = md & (S_ - 1);
    float v = emb[(size_t)seq[md] * D_ + d] + pes[s * D_];
    x[idx] = v;
    xb[idx] = f2b(v);
}

// ---------------- transpose + fp32->bf16: src[K,N] -> dst[N,K] ----------------
// grid(K/32, N/32), block 256
__global__ void transpose_cvt(const float* __restrict__ src, bf16_t* __restrict__ dst,
                              int K, int N) {
    __shared__ float t[32][33];
    int k0 = blockIdx.x * 32, n0 = blockIdx.y * 32;
    int c = threadIdx.x & 31, r = threadIdx.x >> 5;   // r = 0..7
    #pragma unroll
    for (int i = 0; i < 4; i++)
        t[r + i * 8][c] = src[(size_t)(k0 + r + i * 8) * N + n0 + c];
    __syncthreads();
    #pragma unroll
    for (int i = 0; i < 4; i++)
        dst[(size_t)(n0 + r + i * 8) * K + k0 + c] = f2b(t[c][r + i * 8]);
}

// pack q|k|v biases into [256] (pad=0); block 256
__global__ void pack_qkv_bias(const float* __restrict__ bq, const float* __restrict__ bk,
                              const float* __restrict__ bv, float* __restrict__ dst) {
    int n = threadIdx.x;
    float v = 0.f;
    if      (n <  64) v = bq[n];
    else if (n < 128) v = bk[n - 64];
    else if (n < 192) v = bv[n - 128];
    dst[n] = v;
}

// ---------------- bf16 MFMA GEMM: C[M,N] = A[M,K] @ Bt[N,K]^T + bias ----------------
// m97 structure: 128x128 tile, BK=32, 4 waves (2x2), each wave 4x4 of 16x16x32 MFMA.
// grid(N/128, M/128), block 256. K multiple of 32.
template<int RELU, int BF16OUT>
__global__ __launch_bounds__(256)
void gemm_mfma(const bf16_t* __restrict__ A, const bf16_t* __restrict__ Bt,
               const float* __restrict__ bias, float* __restrict__ Cf,
               bf16_t* __restrict__ Cb, int N, int K) {
    __shared__ bf16_t As[128 * 32];
    __shared__ bf16_t Bs[128 * 32];
    const int tid  = threadIdx.x;
    const int w    = tid >> 6, lane = tid & 63;
    const int wm   = w >> 1,   wn   = w & 1;
    const int lm   = lane & 15, quad = lane >> 4;
    const int m0 = blockIdx.y * 128, n0 = blockIdx.x * 128;

    f32x4 acc[4][4];
    #pragma unroll
    for (int i = 0; i < 4; i++)
        #pragma unroll
        for (int j = 0; j < 4; j++) acc[i][j] = (f32x4){0.f, 0.f, 0.f, 0.f};

    const int srow = lane >> 2;            // 0..15 (row within 16-row chunk)
    const int scol = (lane & 3) * 8;       // 0,8,16,24

    for (int k0 = 0; k0 < K; k0 += 32) {
        #pragma unroll
        for (int i = 0; i < 2; i++) {
            const int rt = w * 32 + i * 16;   // wave-uniform chunk base
            gl2lds16(A  + (size_t)(m0 + rt + srow) * K + k0 + scol, As + rt * 32);
            gl2lds16(Bt + (size_t)(n0 + rt + srow) * K + k0 + scol, Bs + rt * 32);
        }
        __syncthreads();
        bf16x8 af[4], bfr[4];
        #pragma unroll
        for (int mi = 0; mi < 4; mi++)
            af[mi] = *(const bf16x8*)(As + (wm * 64 + mi * 16 + lm) * 32 + quad * 8);
        #pragma unroll
        for (int ni = 0; ni < 4; ni++)
            bfr[ni] = *(const bf16x8*)(Bs + (wn * 64 + ni * 16 + lm) * 32 + quad * 8);
        #pragma unroll
        for (int mi = 0; mi < 4; mi++)
            #pragma unroll
            for (int ni = 0; ni < 4; ni++)
                acc[mi][ni] = __builtin_amdgcn_mfma_f32_16x16x32_bf16(
                    af[mi], bfr[ni], acc[mi][ni], 0, 0, 0);
        __syncthreads();
    }

    // C/D layout: col = lane&15, row = quad*4 + r  (m89-verified)
    #pragma unroll
    for (int ni = 0; ni < 4; ni++) {
        const int col = n0 + wn * 64 + ni * 16 + lm;
        const float bv = bias[col];
        #pragma unroll
        for (int mi = 0; mi < 4; mi++) {
            const int rbase = m0 + wm * 64 + mi * 16 + quad * 4;
            #pragma unroll
            for (int r = 0; r < 4; r++) {
                float v = acc[mi][ni][r] + bv;
                if (RELU) v = fmaxf(v, 0.f);
                if (BF16OUT) Cb[(size_t)(rbase + r) * N + col] = f2b(v);
                else         Cf[(size_t)(rbase + r) * N + col] = v;
            }
        }
    }
}

// ---------------- attention (fp32, strided qkv[M,256]: q@0, k@64, v@128) ----------------
__global__ void score_kernel(const float* __restrict__ qkv, float* __restrict__ sc, float scale) {
    int b = blockIdx.z;
    int i0 = blockIdx.y * 64, j0 = blockIdx.x * 64;
    const float* qb = qkv + (size_t)b * S_ * QKVN_;
    const float* kb = qb + 64;
    __shared__ float Qs[64][65], Ks[64][65];
    const int tid = threadIdx.y * 16 + threadIdx.x;
    #pragma unroll
    for (int t = 0; t < 16; t++) {
        int idx = tid + t * 256;
        int r = idx >> 6, c = idx & 63;
        Qs[r][c] = qb[(size_t)(i0 + r) * QKVN_ + c];
        Ks[r][c] = kb[(size_t)(j0 + r) * QKVN_ + c];
    }
    __syncthreads();
    float acc[4][4] = {};
    #pragma unroll 8
    for (int d = 0; d < DK_; d++) {
        float a[4], bb[4];
        #pragma unroll
        for (int i = 0; i < 4; i++) a[i]  = Qs[threadIdx.y * 4 + i][d];
        #pragma unroll
        for (int j = 0; j < 4; j++) bb[j] = Ks[threadIdx.x * 4 + j][d];
        #pragma unroll
        for (int i = 0; i < 4; i++)
            #pragma unroll
            for (int j = 0; j < 4; j++) acc[i][j] = fmaf(a[i], bb[j], acc[i][j]);
    }
    float* sb = sc + (size_t)b * S_ * S_;
    #pragma unroll
    for (int i = 0; i < 4; i++)
        #pragma unroll
        for (int j = 0; j < 4; j++)
            sb[(size_t)(i0 + threadIdx.y * 4 + i) * S_ + j0 + threadIdx.x * 4 + j] = acc[i][j] * scale;
}

__global__ void softmax_kernel(float* __restrict__ sc) {
    float* p = sc + (size_t)blockIdx.x * S_;
    int tid = threadIdx.x;
    float v0 = p[tid], v1 = p[tid + 256];
    float m = fmaxf(v0, v1);
    #pragma unroll
    for (int off = 32; off > 0; off >>= 1) m = fmaxf(m, __shfl_xor(m, off, 64));
    __shared__ float wmax[4], wsum[4];
    int wid = tid >> 6, lane = tid & 63;
    if (lane == 0) wmax[wid] = m;
    __syncthreads();
    m = fmaxf(fmaxf(wmax[0], wmax[1]), fmaxf(wmax[2], wmax[3]));
    v0 = __expf(v0 - m); v1 = __expf(v1 - m);
    float s = v0 + v1;
    #pragma unroll
    for (int off = 32; off > 0; off >>= 1) s += __shfl_xor(s, off, 64);
    if (lane == 0) wsum[wid] = s;
    __syncthreads();
    float inv = 1.0f / (wsum[0] + wsum[1] + wsum[2] + wsum[3]);
    p[tid] = v0 * inv; p[tid + 256] = v1 * inv;
}

// H[b] = P[b][S,S] @ V[b][S,DK] -> bf16 hd; V strided in qkv
__global__ void pv_kernel(const float* __restrict__ P, const float* __restrict__ qkv,
                          bf16_t* __restrict__ H) {
    int b = blockIdx.z;
    const float* Pb = P + (size_t)b * S_ * S_;
    const float* Vb = qkv + (size_t)b * S_ * QKVN_ + 128;
    bf16_t* Hb = H + (size_t)b * S_ * DK_;
    int m0 = blockIdx.y * 64;
    __shared__ float Ps[16][65], Vs[16][65];
    const int tid = threadIdx.y * 16 + threadIdx.x;
    float acc[4][4] = {};
    for (int k0 = 0; k0 < S_; k0 += 16) {
        #pragma unroll
        for (int t = 0; t < 4; t++) {
            int idx = tid + t * 256;
            int r = idx >> 4, c = idx & 15;
            Ps[c][r] = Pb[(size_t)(m0 + r) * S_ + k0 + c];
            int br = idx >> 6, bc = idx & 63;
            Vs[br][bc] = Vb[(size_t)(k0 + br) * QKVN_ + bc];
        }
        __syncthreads();
        #pragma unroll
        for (int kk = 0; kk < 16; kk++) {
            float a[4], bb[4];
            #pragma unroll
            for (int i = 0; i < 4; i++) a[i]  = Ps[kk][threadIdx.y * 4 + i];
            #pragma unroll
            for (int j = 0; j < 4; j++) bb[j] = Vs[kk][threadIdx.x * 4 + j];
            #pragma unroll
            for (int i = 0; i < 4; i++)
                #pragma unroll
                for (int j = 0; j < 4; j++) acc[i][j] = fmaf(a[i], bb[j], acc[i][j]);
        }
        __syncthreads();
    }
    #pragma unroll
    for (int i = 0; i < 4; i++)
        #pragma unroll
        for (int j = 0; j < 4; j++)
            Hb[(size_t)(m0 + threadIdx.y * 4 + i) * DK_ + threadIdx.x * 4 + j] = f2b(acc[i][j]);
}

// dst = BN(x + r); also bf16 copy
__global__ void bn_residual(const float* __restrict__ x, const float* __restrict__ r,
                            const float* __restrict__ g, const float* __restrict__ b,
                            const float* __restrict__ mu, const float* __restrict__ var,
                            float* __restrict__ dst, bf16_t* __restrict__ dstb) {
    int idx = blockIdx.x * 256 + threadIdx.x;
    int d = idx & (D_ - 1);
    float s = x[idx] + r[idx];
    float o = g[d] * (s - mu[d]) * rsqrtf(var[d] + EPS_) + b[d];
    dst[idx] = o;
    dstb[idx] = f2b(o);
}

extern "C" void kernel_launch(void* const* d_in, const int* in_sizes, int n_in,
                              void* d_out, int out_size, void* d_ws, size_t ws_size,
                              hipStream_t stream) {
    const int*   seq = (const int*)  d_in[0];
    const float* emb = (const float*)d_in[1];
    const float* pes = (const float*)d_in[2];
    const float* wq  = (const float*)d_in[3];
    const float* bq  = (const float*)d_in[4];
    const float* wk  = (const float*)d_in[5];
    const float* bk  = (const float*)d_in[6];
    const float* wv  = (const float*)d_in[7];
    const float* bv  = (const float*)d_in[8];
    const float* wo  = (const float*)d_in[9];
    const float* bo  = (const float*)d_in[10];
    const float* ag  = (const float*)d_in[11];
    const float* ab  = (const float*)d_in[12];
    const float* am  = (const float*)d_in[13];
    const float* av  = (const float*)d_in[14];
    const float* w1  = (const float*)d_in[15];
    const float* b1  = (const float*)d_in[16];
    const float* w2  = (const float*)d_in[17];
    const float* b2  = (const float*)d_in[18];
    const float* fg  = (const float*)d_in[19];
    const float* fb  = (const float*)d_in[20];
    const float* fm  = (const float*)d_in[21];
    const float* fv  = (const float*)d_in[22];
    float* out = (float*)d_out;

    // workspace carve (256B aligned), total ~86 MB
    char* p = (char*)d_ws;
    auto alloc = [&](size_t bytes) { char* q = p; p += (bytes + 255) & ~(size_t)255; return q; };
    float*  X     = (float*) alloc((size_t)M_ * D_ * 4);       // 16 MB
    bf16_t* Xb    = (bf16_t*)alloc((size_t)M_ * D_ * 2);       //  8 MB
    float*  qkv   = (float*) alloc((size_t)M_ * QKVN_ * 4);    //  4 MB
    float*  sc    = (float*) alloc((size_t)B_ * S_ * S_ * 4);  //  8 MB
    bf16_t* hdb   = (bf16_t*)alloc((size_t)M_ * DK_ * 2);      // .5 MB
    bf16_t* hb    = (bf16_t*)alloc((size_t)M_ * FF_ * 2);      // 32 MB
    bf16_t* w1t   = (bf16_t*)alloc((size_t)FF_ * D_ * 2);      //  8 MB
    bf16_t* w2t   = (bf16_t*)alloc((size_t)D_ * FF_ * 2);      //  8 MB
    bf16_t* wqkvt = (bf16_t*)alloc((size_t)QKVN_ * D_ * 2);    // .5 MB
    bf16_t* wot   = (bf16_t*)alloc((size_t)D_ * DK_ * 2);      // .125 MB
    float*  bqkv  = (float*) alloc(QKVN_ * 4);
    float*  tmp   = out;   // reuse d_out for fp32 projection results

    dim3 blk(16, 16);
    embed_kernel<<<M_ * D_ / 256, 256, 0, stream>>>(seq, emb, pes, X, Xb);

    for (int l = 0; l < L_; l++) {
        // --- per-layer weight convert/transpose into bf16 [N,K] ---
        hipMemsetAsync(wqkvt + (size_t)192 * D_, 0, (size_t)64 * D_ * 2, stream);
        transpose_cvt<<<dim3(D_ / 32, DK_ / 32), 256, 0, stream>>>(wq + (size_t)l * D_ * DK_, wqkvt,                 D_, DK_);
        transpose_cvt<<<dim3(D_ / 32, DK_ / 32), 256, 0, stream>>>(wk + (size_t)l * D_ * DK_, wqkvt + 64 * D_,       D_, DK_);
        transpose_cvt<<<dim3(D_ / 32, DK_ / 32), 256, 0, stream>>>(wv + (size_t)l * D_ * DK_, wqkvt + 128 * D_,      D_, DK_);
        pack_qkv_bias<<<1, 256, 0, stream>>>(bq + l * DK_, bk + l * DK_, bv + l * DK_, bqkv);
        transpose_cvt<<<dim3(DK_ / 32, D_ / 32), 256, 0, stream>>>(wo + (size_t)l * DK_ * D_, wot, DK_, D_);
        transpose_cvt<<<dim3(D_ / 32, FF_ / 32), 256, 0, stream>>>(w1 + (size_t)l * D_ * FF_, w1t, D_, FF_);
        transpose_cvt<<<dim3(FF_ / 32, D_ / 32), 256, 0, stream>>>(w2 + (size_t)l * FF_ * D_, w2t, FF_, D_);

        // --- QKV (fused, padded N=256) ---
        gemm_mfma<0, 0><<<dim3(QKVN_ / 128, M_ / 128), 256, 0, stream>>>(Xb, wqkvt, bqkv, qkv, nullptr, QKVN_, D_);

        // --- attention ---
        score_kernel<<<dim3(S_ / 64, S_ / 64, B_), blk, 0, stream>>>(qkv, sc, 0.125f);
        softmax_kernel<<<B_ * S_, 256, 0, stream>>>(sc);
        pv_kernel<<<dim3(1, S_ / 64, B_), blk, 0, stream>>>(sc, qkv, hdb);

        // --- output proj + BN ---
        gemm_mfma<0, 0><<<dim3(D_ / 128, M_ / 128), 256, 0, stream>>>(hdb, wot, bo + l * D_, tmp, nullptr, D_, DK_);
        bn_residual<<<M_ * D_ / 256, 256, 0, stream>>>(X, tmp, ag + l * D_, ab + l * D_, am + l * D_, av + l * D_, X, Xb);

        // --- FFN ---
        gemm_mfma<1, 1><<<dim3(FF_ / 128, M_ / 128), 256, 0, stream>>>(Xb, w1t, b1 + l * FF_, nullptr, hb, FF_, D_);
        gemm_mfma<0, 0><<<dim3(D_ / 128, M_ / 128), 256, 0, stream>>>(hb, w2t, b2 + l * D_, tmp, nullptr, D_, FF_);
        bn_residual<<<M_ * D_ / 256, 256, 0, stream>>>(X, tmp, fg + l * D_, fb + l * D_, fm + l * D_, fv + l * D_,
                                                       (l == L_ - 1) ? out : X, Xb);
    }
}

// Round 3
// 1239.806 us; speedup vs baseline: 5.9666x; 1.1405x over previous
//
#include <hip/hip_runtime.h>
#include <hip/hip_bf16.h>
#include <stdint.h>

#define L_  4
#define D_  1024
#define DK_ 64
#define B_  8
#define S_  512
#define FF_ 4096
#define M_  (B_*S_)      // 4096 rows
#define EPS_ 1e-3f
#define QKVN_ 256        // q|k|v|pad packed width

typedef __bf16 bf16_t;
typedef bf16_t bf16x8 __attribute__((ext_vector_type(8)));
typedef float  f32x4  __attribute__((ext_vector_type(4)));

__device__ __forceinline__ bf16_t f2b(float f) {
    union { float f; uint32_t u; } v; v.f = f;
    uint32_t r = v.u + 0x7fff + ((v.u >> 16) & 1);   // RNE
    uint16_t h = (uint16_t)(r >> 16);
    bf16_t o; __builtin_memcpy(&o, &h, 2); return o;
}

__device__ __forceinline__ void gl2lds16(const bf16_t* g, bf16_t* l) {
    __builtin_amdgcn_global_load_lds(
        (__attribute__((address_space(1))) void*)g,
        (__attribute__((address_space(3))) void*)l, 16, 0, 0);
}

// ---------------- embed ----------------
__global__ void embed_kernel(const int* __restrict__ seq, const float* __restrict__ emb,
                             const float* __restrict__ pes, float* __restrict__ x,
                             bf16_t* __restrict__ xb) {
    int idx = blockIdx.x * 256 + threadIdx.x;
    int md  = idx >> 10;
    int d   = idx & (D_ - 1);
    int s   = md & (S_ - 1);
    float v = emb[(size_t)seq[md] * D_ + d] + pes[s * D_];
    x[idx] = v;
    xb[idx] = f2b(v);
}

// ---------------- transpose + fp32->bf16: src[K,N] -> dst[N,K] ----------------
__global__ void transpose_cvt(const float* __restrict__ src, bf16_t* __restrict__ dst,
                              int K, int N) {
    __shared__ float t[32][33];
    int k0 = blockIdx.x * 32, n0 = blockIdx.y * 32;
    int c = threadIdx.x & 31, r = threadIdx.x >> 5;
    #pragma unroll
    for (int i = 0; i < 4; i++)
        t[r + i * 8][c] = src[(size_t)(k0 + r + i * 8) * N + n0 + c];
    __syncthreads();
    #pragma unroll
    for (int i = 0; i < 4; i++)
        dst[(size_t)(n0 + r + i * 8) * K + k0 + c] = f2b(t[c][r + i * 8]);
}

__global__ void pack_qkv_bias(const float* __restrict__ bq, const float* __restrict__ bk,
                              const float* __restrict__ bv, float* __restrict__ dst) {
    int n = threadIdx.x;
    float v = 0.f;
    if      (n <  64) v = bq[n];
    else if (n < 128) v = bk[n - 64];
    else if (n < 192) v = bv[n - 128];
    dst[n] = v;
}

// ---------------- bf16 MFMA GEMM, swizzled-LDS, BK=64 ----------------
// LDS layout (per tile, elements of bf16): offset(c,kg,r) = ((c*8+kg)*16 + r)*8
//   c = 16-row chunk (0..7), kg = 8-col k-group (0..7), r = row in chunk (0..15)
// Each ds_read_b128 fragment load then reads 256 contiguous LDS bytes per quad
// (2 lanes/bank -> conflict-free per m136).
// MODE 0: Cf fp32 = acc + bias          (wo proj)
// MODE 1: Cb bf16 = relu(acc + bias)    (FFN1)
// MODE 2: bf16 K-split partial, no bias (QKV, FFN2); partial z<2 -> P01, z>=2 -> P23
template<int MODE>
__global__ __launch_bounds__(256)
void gemm_mfma2(const bf16_t* __restrict__ A, const bf16_t* __restrict__ Bt,
                const float* __restrict__ bias, float* __restrict__ Cf,
                bf16_t* __restrict__ Cb, bf16_t* __restrict__ P01, bf16_t* __restrict__ P23,
                int N, int K, int kChunk, size_t strideZ) {
    __shared__ bf16_t As[128 * 64];
    __shared__ bf16_t Bs[128 * 64];
    const int tid  = threadIdx.x;
    const int w    = tid >> 6, lane = tid & 63;
    const int wm   = w >> 1,   wn   = w & 1;
    const int lm   = lane & 15, quad = lane >> 4;
    const int m0 = blockIdx.y * 128, n0 = blockIdx.x * 128;
    const int z  = blockIdx.z;
    const int kBeg = z * kChunk, kEnd = kBeg + kChunk;
    const int r16 = lane & 15;     // staging: row within chunk
    const int kg4 = lane >> 4;     // staging: k-group within half

    f32x4 acc[4][4];
    #pragma unroll
    for (int i = 0; i < 4; i++)
        #pragma unroll
        for (int j = 0; j < 4; j++) acc[i][j] = (f32x4){0.f, 0.f, 0.f, 0.f};

    for (int k0 = kBeg; k0 < kEnd; k0 += 64) {
        #pragma unroll
        for (int c2 = 0; c2 < 2; c2++) {
            const int c = w * 2 + c2;
            #pragma unroll
            for (int h = 0; h < 2; h++) {
                gl2lds16(A  + (size_t)(m0 + c * 16 + r16) * K + k0 + (h * 4 + kg4) * 8,
                         As + (size_t)(c * 8 + h * 4) * 128);
                gl2lds16(Bt + (size_t)(n0 + c * 16 + r16) * K + k0 + (h * 4 + kg4) * 8,
                         Bs + (size_t)(c * 8 + h * 4) * 128);
            }
        }
        __syncthreads();
        #pragma unroll
        for (int s = 0; s < 2; s++) {
            bf16x8 af[4], bfr[4];
            #pragma unroll
            for (int mi = 0; mi < 4; mi++)
                af[mi] = *(const bf16x8*)(As + ((wm * 4 + mi) * 8 + s * 4 + quad) * 128 + lm * 8);
            #pragma unroll
            for (int ni = 0; ni < 4; ni++)
                bfr[ni] = *(const bf16x8*)(Bs + ((wn * 4 + ni) * 8 + s * 4 + quad) * 128 + lm * 8);
            #pragma unroll
            for (int mi = 0; mi < 4; mi++)
                #pragma unroll
                for (int ni = 0; ni < 4; ni++)
                    acc[mi][ni] = __builtin_amdgcn_mfma_f32_16x16x32_bf16(
                        af[mi], bfr[ni], acc[mi][ni], 0, 0, 0);
        }
        __syncthreads();
    }

    bf16_t* Pz = nullptr;
    if (MODE == 2) Pz = (z < 2) ? (P01 + (size_t)z * strideZ) : (P23 + (size_t)(z - 2) * strideZ);

    #pragma unroll
    for (int ni = 0; ni < 4; ni++) {
        const int col = n0 + wn * 64 + ni * 16 + lm;
        const float bv = (MODE == 2) ? 0.f : bias[col];
        #pragma unroll
        for (int mi = 0; mi < 4; mi++) {
            const int rbase = m0 + wm * 64 + mi * 16 + quad * 4;
            #pragma unroll
            for (int r = 0; r < 4; r++) {
                float v = acc[mi][ni][r] + bv;
                if (MODE == 0) Cf[(size_t)(rbase + r) * N + col] = v;
                if (MODE == 1) Cb[(size_t)(rbase + r) * N + col] = f2b(fmaxf(v, 0.f));
                if (MODE == 2) Pz[(size_t)(rbase + r) * N + col] = f2b(v);
            }
        }
    }
}

// qkv partial sum (4 bf16 partials) + bias -> bf16 qkv
__global__ void qkv_reduce(const bf16_t* __restrict__ P, const float* __restrict__ bias,
                           bf16_t* __restrict__ dst) {
    int idx = blockIdx.x * 256 + threadIdx.x;    // M_*QKVN_
    int n = idx & (QKVN_ - 1);
    float s = bias[n];
    #pragma unroll
    for (int zz = 0; zz < 4; zz++) s += (float)P[(size_t)zz * M_ * QKVN_ + idx];
    dst[idx] = f2b(s);
}

// ---------------- attention (bf16 qkv[M,256]: q@0, k@64, v@128) ----------------
__global__ void score_kernel(const bf16_t* __restrict__ qkv, float* __restrict__ sc, float scale) {
    int b = blockIdx.z;
    int i0 = blockIdx.y * 64, j0 = blockIdx.x * 64;
    const bf16_t* qb = qkv + (size_t)b * S_ * QKVN_;
    const bf16_t* kb = qb + 64;
    __shared__ float Qs[64][65], Ks[64][65];
    const int tid = threadIdx.y * 16 + threadIdx.x;
    #pragma unroll
    for (int t = 0; t < 16; t++) {
        int idx = tid + t * 256;
        int r = idx >> 6, c = idx & 63;
        Qs[r][c] = (float)qb[(size_t)(i0 + r) * QKVN_ + c];
        Ks[r][c] = (float)kb[(size_t)(j0 + r) * QKVN_ + c];
    }
    __syncthreads();
    float acc[4][4] = {};
    #pragma unroll 8
    for (int d = 0; d < DK_; d++) {
        float a[4], bb[4];
        #pragma unroll
        for (int i = 0; i < 4; i++) a[i]  = Qs[threadIdx.y * 4 + i][d];
        #pragma unroll
        for (int j = 0; j < 4; j++) bb[j] = Ks[threadIdx.x * 4 + j][d];
        #pragma unroll
        for (int i = 0; i < 4; i++)
            #pragma unroll
            for (int j = 0; j < 4; j++) acc[i][j] = fmaf(a[i], bb[j], acc[i][j]);
    }
    float* sb = sc + (size_t)b * S_ * S_;
    #pragma unroll
    for (int i = 0; i < 4; i++)
        #pragma unroll
        for (int j = 0; j < 4; j++)
            sb[(size_t)(i0 + threadIdx.y * 4 + i) * S_ + j0 + threadIdx.x * 4 + j] = acc[i][j] * scale;
}

__global__ void softmax_kernel(float* __restrict__ sc) {
    float* p = sc + (size_t)blockIdx.x * S_;
    int tid = threadIdx.x;
    float v0 = p[tid], v1 = p[tid + 256];
    float m = fmaxf(v0, v1);
    #pragma unroll
    for (int off = 32; off > 0; off >>= 1) m = fmaxf(m, __shfl_xor(m, off, 64));
    __shared__ float wmax[4], wsum[4];
    int wid = tid >> 6, lane = tid & 63;
    if (lane == 0) wmax[wid] = m;
    __syncthreads();
    m = fmaxf(fmaxf(wmax[0], wmax[1]), fmaxf(wmax[2], wmax[3]));
    v0 = __expf(v0 - m); v1 = __expf(v1 - m);
    float s = v0 + v1;
    #pragma unroll
    for (int off = 32; off > 0; off >>= 1) s += __shfl_xor(s, off, 64);
    if (lane == 0) wsum[wid] = s;
    __syncthreads();
    float inv = 1.0f / (wsum[0] + wsum[1] + wsum[2] + wsum[3]);
    p[tid] = v0 * inv; p[tid + 256] = v1 * inv;
}

// pv with K-split: grid(4 splits, S/64, B). Partial fp32 out Hp[split][M,DK].
__global__ void pv_kernel(const float* __restrict__ P, const bf16_t* __restrict__ qkv,
                          float* __restrict__ Hp) {
    int b = blockIdx.z, sp = blockIdx.x;
    const float*  Pb = P + (size_t)b * S_ * S_;
    const bf16_t* Vb = qkv + (size_t)b * S_ * QKVN_ + 128;
    float* Hb = Hp + (size_t)sp * M_ * DK_ + (size_t)b * S_ * DK_;
    int m0 = blockIdx.y * 64;
    __shared__ float Ps[16][65], Vs[16][65];
    const int tid = threadIdx.y * 16 + threadIdx.x;
    float acc[4][4] = {};
    for (int k0 = sp * 128; k0 < sp * 128 + 128; k0 += 16) {
        #pragma unroll
        for (int t = 0; t < 4; t++) {
            int idx = tid + t * 256;
            int r = idx >> 4, c = idx & 15;
            Ps[c][r] = Pb[(size_t)(m0 + r) * S_ + k0 + c];
            int br = idx >> 6, bc = idx & 63;
            Vs[br][bc] = (float)Vb[(size_t)(k0 + br) * QKVN_ + bc];
        }
        __syncthreads();
        #pragma unroll
        for (int kk = 0; kk < 16; kk++) {
            float a[4], bb[4];
            #pragma unroll
            for (int i = 0; i < 4; i++) a[i]  = Ps[kk][threadIdx.y * 4 + i];
            #pragma unroll
            for (int j = 0; j < 4; j++) bb[j] = Vs[kk][threadIdx.x * 4 + j];
            #pragma unroll
            for (int i = 0; i < 4; i++)
                #pragma unroll
                for (int j = 0; j < 4; j++) acc[i][j] = fmaf(a[i], bb[j], acc[i][j]);
        }
        __syncthreads();
    }
    #pragma unroll
    for (int i = 0; i < 4; i++)
        #pragma unroll
        for (int j = 0; j < 4; j++)
            Hb[(size_t)(m0 + threadIdx.y * 4 + i) * DK_ + threadIdx.x * 4 + j] = acc[i][j];
}

__global__ void pv_reduce(const float* __restrict__ Hp, bf16_t* __restrict__ hdb) {
    int idx = blockIdx.x * 256 + threadIdx.x;    // M_*DK_
    float s = Hp[idx] + Hp[(size_t)M_ * DK_ + idx]
            + Hp[2 * (size_t)M_ * DK_ + idx] + Hp[3 * (size_t)M_ * DK_ + idx];
    hdb[idx] = f2b(s);
}

// bn1: dst = BN(x + r_fp32), r from wo-proj
__global__ void bn_residual(const float* __restrict__ x, const float* __restrict__ r,
                            const float* __restrict__ g, const float* __restrict__ b,
                            const float* __restrict__ mu, const float* __restrict__ var,
                            float* __restrict__ dst, bf16_t* __restrict__ dstb) {
    int idx = blockIdx.x * 256 + threadIdx.x;
    int d = idx & (D_ - 1);
    float s = x[idx] + r[idx];
    float o = g[d] * (s - mu[d]) * rsqrtf(var[d] + EPS_) + b[d];
    dst[idx] = o;
    dstb[idx] = f2b(o);
}

// bn2: dst = BN(x + bias + sum of 4 bf16 K-split partials)
__global__ void bn_residual4(const float* __restrict__ x,
                             const bf16_t* __restrict__ p01, const bf16_t* __restrict__ p23,
                             const float* __restrict__ bias,
                             const float* __restrict__ g, const float* __restrict__ b,
                             const float* __restrict__ mu, const float* __restrict__ var,
                             float* __restrict__ dst, bf16_t* __restrict__ dstb) {
    int idx = blockIdx.x * 256 + threadIdx.x;
    int d = idx & (D_ - 1);
    float r = bias[d] + (float)p01[idx] + (float)p01[(size_t)M_ * D_ + idx]
            + (float)p23[idx] + (float)p23[(size_t)M_ * D_ + idx];
    float s = x[idx] + r;
    float o = g[d] * (s - mu[d]) * rsqrtf(var[d] + EPS_) + b[d];
    dst[idx] = o;
    if (dstb) dstb[idx] = f2b(o);
}

extern "C" void kernel_launch(void* const* d_in, const int* in_sizes, int n_in,
                              void* d_out, int out_size, void* d_ws, size_t ws_size,
                              hipStream_t stream) {
    const int*   seq = (const int*)  d_in[0];
    const float* emb = (const float*)d_in[1];
    const float* pes = (const float*)d_in[2];
    const float* wq  = (const float*)d_in[3];
    const float* bq  = (const float*)d_in[4];
    const float* wk  = (const float*)d_in[5];
    const float* bk  = (const float*)d_in[6];
    const float* wv  = (const float*)d_in[7];
    const float* bv  = (const float*)d_in[8];
    const float* wo  = (const float*)d_in[9];
    const float* bo  = (const float*)d_in[10];
    const float* ag  = (const float*)d_in[11];
    const float* ab  = (const float*)d_in[12];
    const float* am  = (const float*)d_in[13];
    const float* av  = (const float*)d_in[14];
    const float* w1  = (const float*)d_in[15];
    const float* b1  = (const float*)d_in[16];
    const float* w2  = (const float*)d_in[17];
    const float* b2  = (const float*)d_in[18];
    const float* fg  = (const float*)d_in[19];
    const float* fb  = (const float*)d_in[20];
    const float* fm  = (const float*)d_in[21];
    const float* fv  = (const float*)d_in[22];
    float* out = (float*)d_out;

    // workspace carve (~91 MB, <= 92.6 MB proven in round 1)
    char* p = (char*)d_ws;
    auto alloc = [&](size_t bytes) { char* q = p; p += (bytes + 255) & ~(size_t)255; return q; };
    float*  X     = (float*) alloc((size_t)M_ * D_ * 4);        // 16 MB
    bf16_t* Xb    = (bf16_t*)alloc((size_t)M_ * D_ * 2);        //  8 MB
    bf16_t* qkvb  = (bf16_t*)alloc((size_t)M_ * QKVN_ * 2);     //  2 MB
    float*  sc    = (float*) alloc((size_t)B_ * S_ * S_ * 4);   //  8 MB
    bf16_t* hdb   = (bf16_t*)alloc((size_t)M_ * DK_ * 2);       // .5 MB
    bf16_t* hb    = (bf16_t*)alloc((size_t)M_ * FF_ * 2);       // 32 MB
    bf16_t* wff   = (bf16_t*)alloc((size_t)FF_ * D_ * 2);       //  8 MB (w1t / w2t, time-shared)
    bf16_t* wqkvt = (bf16_t*)alloc((size_t)QKVN_ * D_ * 2);     // .5 MB
    bf16_t* wot   = (bf16_t*)alloc((size_t)D_ * DK_ * 2);       // .125 MB
    float*  bqkv  = (float*) alloc(QKVN_ * 4);
    bf16_t* pbuf  = (bf16_t*)alloc((size_t)2 * M_ * D_ * 2);    // 16 MB (FFN2 partials z=2,3)
    float*  tmp   = out;                                        // fp32 wo-proj result

    dim3 blk(16, 16);
    embed_kernel<<<M_ * D_ / 256, 256, 0, stream>>>(seq, emb, pes, X, Xb);

    for (int l = 0; l < L_; l++) {
        // --- weight prep ---
        hipMemsetAsync(wqkvt + (size_t)192 * D_, 0, (size_t)64 * D_ * 2, stream);
        transpose_cvt<<<dim3(D_ / 32, DK_ / 32), 256, 0, stream>>>(wq + (size_t)l * D_ * DK_, wqkvt,            D_, DK_);
        transpose_cvt<<<dim3(D_ / 32, DK_ / 32), 256, 0, stream>>>(wk + (size_t)l * D_ * DK_, wqkvt + 64 * D_,  D_, DK_);
        transpose_cvt<<<dim3(D_ / 32, DK_ / 32), 256, 0, stream>>>(wv + (size_t)l * D_ * DK_, wqkvt + 128 * D_, D_, DK_);
        pack_qkv_bias<<<1, 256, 0, stream>>>(bq + l * DK_, bk + l * DK_, bv + l * DK_, bqkv);
        transpose_cvt<<<dim3(DK_ / 32, D_ / 32), 256, 0, stream>>>(wo + (size_t)l * DK_ * D_, wot, DK_, D_);
        transpose_cvt<<<dim3(D_ / 32, FF_ / 32), 256, 0, stream>>>(w1 + (size_t)l * D_ * FF_, wff, D_, FF_);

        // --- QKV: split-K=4, bf16 partials in d_out (4 x 2 MB) ---
        gemm_mfma2<2><<<dim3(QKVN_ / 128, M_ / 128, 4), 256, 0, stream>>>(
            Xb, wqkvt, nullptr, nullptr, nullptr,
            (bf16_t*)out, (bf16_t*)out + 2 * (size_t)M_ * QKVN_,
            QKVN_, D_, D_ / 4, (size_t)M_ * QKVN_);
        qkv_reduce<<<M_ * QKVN_ / 256, 256, 0, stream>>>((const bf16_t*)out, bqkv, qkvb);

        // --- attention ---
        score_kernel<<<dim3(S_ / 64, S_ / 64, B_), blk, 0, stream>>>(qkvb, sc, 0.125f);
        softmax_kernel<<<B_ * S_, 256, 0, stream>>>(sc);
        pv_kernel<<<dim3(4, S_ / 64, B_), blk, 0, stream>>>(sc, qkvb, (float*)out);
        pv_reduce<<<M_ * DK_ / 256, 256, 0, stream>>>((const float*)out, hdb);

        // --- output proj (fp32 into d_out) + BN1 ---
        gemm_mfma2<0><<<dim3(D_ / 128, M_ / 128, 1), 256, 0, stream>>>(
            hdb, wot, bo + l * D_, tmp, nullptr, nullptr, nullptr, D_, DK_, DK_, 0);
        bn_residual<<<M_ * D_ / 256, 256, 0, stream>>>(X, tmp, ag + l * D_, ab + l * D_,
                                                       am + l * D_, av + l * D_, X, Xb);

        // --- FFN1 (bf16 out + relu) ---
        gemm_mfma2<1><<<dim3(FF_ / 128, M_ / 128, 1), 256, 0, stream>>>(
            Xb, wff, b1 + l * FF_, nullptr, hb, nullptr, nullptr, FF_, D_, D_, 0);

        // --- FFN2: split-K=4, partials z=0,1 -> d_out, z=2,3 -> pbuf ---
        transpose_cvt<<<dim3(FF_ / 32, D_ / 32), 256, 0, stream>>>(w2 + (size_t)l * FF_ * D_, wff, FF_, D_);
        gemm_mfma2<2><<<dim3(D_ / 128, M_ / 128, 4), 256, 0, stream>>>(
            hb, wff, nullptr, nullptr, nullptr,
            (bf16_t*)out, pbuf, D_, FF_, FF_ / 4, (size_t)M_ * D_);

        bool last = (l == L_ - 1);
        bn_residual4<<<M_ * D_ / 256, 256, 0, stream>>>(
            X, (const bf16_t*)out, pbuf, b2 + l * D_,
            fg + l * D_, fb + l * D_, fm + l * D_, fv + l * D_,
            X, last ? nullptr : Xb);
        if (last)
            hipMemcpyAsync(out, X, (size_t)M_ * D_ * 4, hipMemcpyDeviceToDevice, stream);
    }
}

// Round 4
// 984.550 us; speedup vs baseline: 7.5135x; 1.2593x over previous
//
#include <hip/hip_runtime.h>
#include <hip/hip_bf16.h>
#include <stdint.h>

#define L_  4
#define D_  1024
#define DK_ 64
#define B_  8
#define S_  512
#define FF_ 4096
#define M_  (B_*S_)      // 4096 rows
#define EPS_ 1e-3f
#define QKVN_ 256        // q|k|v|pad packed width

typedef __bf16 bf16_t;
typedef bf16_t bf16x8 __attribute__((ext_vector_type(8)));
typedef float  f32x4  __attribute__((ext_vector_type(4)));

__device__ __forceinline__ bf16_t f2b(float f) {
    union { float f; uint32_t u; } v; v.f = f;
    uint32_t r = v.u + 0x7fff + ((v.u >> 16) & 1);   // RNE
    uint16_t h = (uint16_t)(r >> 16);
    bf16_t o; __builtin_memcpy(&o, &h, 2); return o;
}

__device__ __forceinline__ void gl2lds16(const bf16_t* g, bf16_t* l) {
    __builtin_amdgcn_global_load_lds(
        (__attribute__((address_space(1))) void*)g,
        (__attribute__((address_space(3))) void*)l, 16, 0, 0);
}

// ---------------- embed ----------------
__global__ void embed_kernel(const int* __restrict__ seq, const float* __restrict__ emb,
                             const float* __restrict__ pes, float* __restrict__ x,
                             bf16_t* __restrict__ xb) {
    int idx = blockIdx.x * 256 + threadIdx.x;
    int md  = idx >> 10;
    int d   = idx & (D_ - 1);
    int s   = md & (S_ - 1);
    float v = emb[(size_t)seq[md] * D_ + d] + pes[s * D_];
    x[idx] = v;
    xb[idx] = f2b(v);
}

// ---------------- fused per-layer weight prep ----------------
// 32x32 transpose+cvt tile: src[K,N] fp32 -> dst[N,K] bf16
__device__ __forceinline__ void tile_tr(const float* __restrict__ src, bf16_t* __restrict__ dst,
                                        int K, int N, int kb, int nb, float (*t)[33]) {
    int k0 = kb * 32, n0 = nb * 32;
    int c = threadIdx.x & 31, r = threadIdx.x >> 5;   // r = 0..7
    #pragma unroll
    for (int i = 0; i < 4; i++)
        t[r + i * 8][c] = src[(size_t)(k0 + r + i * 8) * N + n0 + c];
    __syncthreads();
    #pragma unroll
    for (int i = 0; i < 4; i++)
        dst[(size_t)(n0 + r + i * 8) * K + k0 + c] = f2b(t[c][r + i * 8]);
}

// one launch per layer: w1(4096) | w2(4096) | wq,wk,wv(192) | wo(64) | zero(16) | bias(1)
__global__ void prep_weights(const float* __restrict__ wq, const float* __restrict__ wk,
                             const float* __restrict__ wv, const float* __restrict__ wo,
                             const float* __restrict__ w1, const float* __restrict__ w2,
                             const float* __restrict__ bq, const float* __restrict__ bk,
                             const float* __restrict__ bv,
                             bf16_t* __restrict__ wqkvt, bf16_t* __restrict__ wot,
                             bf16_t* __restrict__ w1t, bf16_t* __restrict__ w2t,
                             float* __restrict__ bqkv) {
    __shared__ float t[32][33];
    int bid = blockIdx.x;
    if (bid < 4096) {                       // w1: K=D_, N=FF_
        tile_tr(w1, w1t, D_, FF_, bid & 31, bid >> 5, t);
    } else if (bid < 8192) {                // w2: K=FF_, N=D_
        int rem = bid - 4096;
        tile_tr(w2, w2t, FF_, D_, rem & 127, rem >> 7, t);
    } else if (bid < 8384) {                // wq/wk/wv: K=D_, N=64
        int rem = bid - 8192;
        int which = rem >> 6; rem &= 63;
        const float* src = which == 0 ? wq : (which == 1 ? wk : wv);
        tile_tr(src, wqkvt + (size_t)which * 64 * D_, D_, DK_, rem & 31, rem >> 5, t);
    } else if (bid < 8448) {                // wo: K=64, N=D_
        int rem = bid - 8384;
        tile_tr(wo, wot, DK_, D_, rem & 1, rem >> 1, t);
    } else if (bid < 8464) {                // zero pad rows 192..255 of wqkvt
        int rem = bid - 8448;
        bf16_t* z = wqkvt + (size_t)192 * D_ + rem * 4096;
        for (int i = threadIdx.x; i < 4096; i += 256) z[i] = (bf16_t)0.f;
    } else {                                // bias pack
        int n = threadIdx.x;
        float v = 0.f;
        if      (n <  64) v = bq[n];
        else if (n < 128) v = bk[n - 64];
        else if (n < 192) v = bv[n - 128];
        bqkv[n] = v;
    }
}

// ---------------- bf16 MFMA GEMM, coalesced + conflict-free staging ----------------
// LDS layout: elem(row, kchunk) at row*64 + ((kchunk ^ (row&7))*8)   [elements, BK=64, 8-elem chunks]
// Staging instr = 8 rows x 128 B; lane l -> row l>>3, chunk (l&7)^(l>>3)  => global 128-B segments.
// Fragment ds_read_b128: per quad-group, chunk' = const ^ (lm&7) => 2 lanes/bank = free.
// MODE 1: Cb = relu(acc+bias) bf16          (FFN1)
// MODE 2: partial bf16, no bias: Cb + z*strideZ  (QKV z4, FFN2 z2)
// MODE 3: fused BN epilogue: o = g*(X + acc + bias - mu)*rsqrt(var+eps) + b -> Xf, Xb   (wo proj)
template<int MODE>
__global__ __launch_bounds__(256)
void gemm_mfma3(const bf16_t* __restrict__ A, const bf16_t* __restrict__ Bt,
                const float* __restrict__ bias, bf16_t* __restrict__ Cb,
                const float* __restrict__ Xin, float* __restrict__ Xf, bf16_t* __restrict__ Xb,
                const float* __restrict__ g, const float* __restrict__ bb,
                const float* __restrict__ mu, const float* __restrict__ var,
                int N, int K, int kChunk, size_t strideZ) {
    __shared__ bf16_t As[128 * 64];
    __shared__ bf16_t Bs[128 * 64];
    const int tid  = threadIdx.x;
    const int w    = tid >> 6, lane = tid & 63;
    const int wm   = w >> 1,   wn   = w & 1;
    const int lm   = lane & 15, quad = lane >> 4;
    const int m0 = blockIdx.y * 128, n0 = blockIdx.x * 128;
    const int kBeg = blockIdx.z * kChunk, kEnd = kBeg + kChunk;
    const int lrow = lane >> 3;              // 0..7
    const int lk   = (lane & 7) ^ lrow;      // xor-swizzled chunk to fetch

    f32x4 acc[4][4];
    #pragma unroll
    for (int i = 0; i < 4; i++)
        #pragma unroll
        for (int j = 0; j < 4; j++) acc[i][j] = (f32x4){0.f, 0.f, 0.f, 0.f};

    for (int k0 = kBeg; k0 < kEnd; k0 += 64) {
        #pragma unroll
        for (int i = 0; i < 4; i++) {
            const int r0 = w * 32 + i * 8;
            gl2lds16(A  + (size_t)(m0 + r0 + lrow) * K + k0 + lk * 8, As + r0 * 64);
            gl2lds16(Bt + (size_t)(n0 + r0 + lrow) * K + k0 + lk * 8, Bs + r0 * 64);
        }
        __syncthreads();
        #pragma unroll
        for (int s = 0; s < 2; s++) {
            bf16x8 af[4], bfr[4];
            #pragma unroll
            for (int mi = 0; mi < 4; mi++) {
                const int ra = wm * 64 + mi * 16 + lm;
                af[mi] = *(const bf16x8*)(As + ra * 64 + (((s * 4 + quad) ^ (lm & 7)) * 8));
            }
            #pragma unroll
            for (int ni = 0; ni < 4; ni++) {
                const int rb = wn * 64 + ni * 16 + lm;
                bfr[ni] = *(const bf16x8*)(Bs + rb * 64 + (((s * 4 + quad) ^ (lm & 7)) * 8));
            }
            #pragma unroll
            for (int mi = 0; mi < 4; mi++)
                #pragma unroll
                for (int ni = 0; ni < 4; ni++)
                    acc[mi][ni] = __builtin_amdgcn_mfma_f32_16x16x32_bf16(
                        af[mi], bfr[ni], acc[mi][ni], 0, 0, 0);
        }
        __syncthreads();
    }

    bf16_t* Pz = (MODE == 2) ? Cb + (size_t)blockIdx.z * strideZ : Cb;

    #pragma unroll
    for (int ni = 0; ni < 4; ni++) {
        const int col = n0 + wn * 64 + ni * 16 + lm;
        float bv = 0.f, gv = 0.f, bbv = 0.f, muv = 0.f, rsv = 0.f;
        if (MODE != 2) bv = bias[col];
        if (MODE == 3) {
            gv = g[col]; bbv = bb[col]; muv = mu[col];
            rsv = rsqrtf(var[col] + EPS_);
        }
        #pragma unroll
        for (int mi = 0; mi < 4; mi++) {
            const int rbase = m0 + wm * 64 + mi * 16 + quad * 4;
            #pragma unroll
            for (int r = 0; r < 4; r++) {
                const size_t idx = (size_t)(rbase + r) * N + col;
                float v = acc[mi][ni][r] + bv;
                if (MODE == 1) Cb[idx] = f2b(fmaxf(v, 0.f));
                if (MODE == 2) Pz[idx] = f2b(v);
                if (MODE == 3) {
                    float s = Xin[idx] + v;
                    float o = gv * (s - muv) * rsv + bbv;
                    Xf[idx] = o;
                    Xb[idx] = f2b(o);
                }
            }
        }
    }
}

// qkv partial sum (4 bf16 partials in d_out) + bias -> bf16 qkv
__global__ void qkv_reduce(const bf16_t* __restrict__ P, const float* __restrict__ bias,
                           bf16_t* __restrict__ dst) {
    int idx = blockIdx.x * 256 + threadIdx.x;    // M_*QKVN_
    int n = idx & (QKVN_ - 1);
    float s = bias[n];
    #pragma unroll
    for (int zz = 0; zz < 4; zz++) s += (float)P[(size_t)zz * M_ * QKVN_ + idx];
    dst[idx] = f2b(s);
}

// ---------------- attention (bf16 qkv[M,256]: q@0, k@64, v@128) ----------------
__global__ void score_kernel(const bf16_t* __restrict__ qkv, float* __restrict__ sc, float scale) {
    int b = blockIdx.z;
    int i0 = blockIdx.y * 64, j0 = blockIdx.x * 64;
    const bf16_t* qb = qkv + (size_t)b * S_ * QKVN_;
    const bf16_t* kb = qb + 64;
    __shared__ float Qs[64][65], Ks[64][65];
    const int tid = threadIdx.y * 16 + threadIdx.x;
    #pragma unroll
    for (int t = 0; t < 16; t++) {
        int idx = tid + t * 256;
        int r = idx >> 6, c = idx & 63;
        Qs[r][c] = (float)qb[(size_t)(i0 + r) * QKVN_ + c];
        Ks[r][c] = (float)kb[(size_t)(j0 + r) * QKVN_ + c];
    }
    __syncthreads();
    float acc[4][4] = {};
    #pragma unroll 8
    for (int d = 0; d < DK_; d++) {
        float a[4], bbv[4];
        #pragma unroll
        for (int i = 0; i < 4; i++) a[i]   = Qs[threadIdx.y * 4 + i][d];
        #pragma unroll
        for (int j = 0; j < 4; j++) bbv[j] = Ks[threadIdx.x * 4 + j][d];
        #pragma unroll
        for (int i = 0; i < 4; i++)
            #pragma unroll
            for (int j = 0; j < 4; j++) acc[i][j] = fmaf(a[i], bbv[j], acc[i][j]);
    }
    float* sb = sc + (size_t)b * S_ * S_;
    #pragma unroll
    for (int i = 0; i < 4; i++)
        #pragma unroll
        for (int j = 0; j < 4; j++)
            sb[(size_t)(i0 + threadIdx.y * 4 + i) * S_ + j0 + threadIdx.x * 4 + j] = acc[i][j] * scale;
}

__global__ void softmax_kernel(float* __restrict__ sc) {
    float* p = sc + (size_t)blockIdx.x * S_;
    int tid = threadIdx.x;
    float v0 = p[tid], v1 = p[tid + 256];
    float m = fmaxf(v0, v1);
    #pragma unroll
    for (int off = 32; off > 0; off >>= 1) m = fmaxf(m, __shfl_xor(m, off, 64));
    __shared__ float wmax[4], wsum[4];
    int wid = tid >> 6, lane = tid & 63;
    if (lane == 0) wmax[wid] = m;
    __syncthreads();
    m = fmaxf(fmaxf(wmax[0], wmax[1]), fmaxf(wmax[2], wmax[3]));
    v0 = __expf(v0 - m); v1 = __expf(v1 - m);
    float s = v0 + v1;
    #pragma unroll
    for (int off = 32; off > 0; off >>= 1) s += __shfl_xor(s, off, 64);
    if (lane == 0) wsum[wid] = s;
    __syncthreads();
    float inv = 1.0f / (wsum[0] + wsum[1] + wsum[2] + wsum[3]);
    p[tid] = v0 * inv; p[tid + 256] = v1 * inv;
}

// pv K-split: grid(4, S/64, B); fp32 partials Hp[split][M,DK] (in d_out, 4 MB)
__global__ void pv_kernel(const float* __restrict__ P, const bf16_t* __restrict__ qkv,
                          float* __restrict__ Hp) {
    int b = blockIdx.z, sp = blockIdx.x;
    const float*  Pb = P + (size_t)b * S_ * S_;
    const bf16_t* Vb = qkv + (size_t)b * S_ * QKVN_ + 128;
    float* Hb = Hp + (size_t)sp * M_ * DK_ + (size_t)b * S_ * DK_;
    int m0 = blockIdx.y * 64;
    __shared__ float Ps[16][65], Vs[16][65];
    const int tid = threadIdx.y * 16 + threadIdx.x;
    float acc[4][4] = {};
    for (int k0 = sp * 128; k0 < sp * 128 + 128; k0 += 16) {
        #pragma unroll
        for (int t = 0; t < 4; t++) {
            int idx = tid + t * 256;
            int r = idx >> 4, c = idx & 15;
            Ps[c][r] = Pb[(size_t)(m0 + r) * S_ + k0 + c];
            int br = idx >> 6, bc = idx & 63;
            Vs[br][bc] = (float)Vb[(size_t)(k0 + br) * QKVN_ + bc];
        }
        __syncthreads();
        #pragma unroll
        for (int kk = 0; kk < 16; kk++) {
            float a[4], bbv[4];
            #pragma unroll
            for (int i = 0; i < 4; i++) a[i]   = Ps[kk][threadIdx.y * 4 + i];
            #pragma unroll
            for (int j = 0; j < 4; j++) bbv[j] = Vs[kk][threadIdx.x * 4 + j];
            #pragma unroll
            for (int i = 0; i < 4; i++)
                #pragma unroll
                for (int j = 0; j < 4; j++) acc[i][j] = fmaf(a[i], bbv[j], acc[i][j]);
        }
        __syncthreads();
    }
    #pragma unroll
    for (int i = 0; i < 4; i++)
        #pragma unroll
        for (int j = 0; j < 4; j++)
            Hb[(size_t)(m0 + threadIdx.y * 4 + i) * DK_ + threadIdx.x * 4 + j] = acc[i][j];
}

__global__ void pv_reduce(const float* __restrict__ Hp, bf16_t* __restrict__ hdb) {
    int idx = blockIdx.x * 256 + threadIdx.x;    // M_*DK_
    float s = Hp[idx] + Hp[(size_t)M_ * DK_ + idx]
            + Hp[2 * (size_t)M_ * DK_ + idx] + Hp[3 * (size_t)M_ * DK_ + idx];
    hdb[idx] = f2b(s);
}

// bn2: dst = BN(x + bias + sum of 2 bf16 K-split partials (in d_out))
__global__ void bn_residual2(const float* __restrict__ x, const bf16_t* __restrict__ p,
                             const float* __restrict__ bias,
                             const float* __restrict__ g, const float* __restrict__ b,
                             const float* __restrict__ mu, const float* __restrict__ var,
                             float* __restrict__ dst, bf16_t* __restrict__ dstb) {
    int idx = blockIdx.x * 256 + threadIdx.x;
    int d = idx & (D_ - 1);
    float r = bias[d] + (float)p[idx] + (float)p[(size_t)M_ * D_ + idx];
    float s = x[idx] + r;
    float o = g[d] * (s - mu[d]) * rsqrtf(var[d] + EPS_) + b[d];
    dst[idx] = o;
    dstb[idx] = f2b(o);
}

extern "C" void kernel_launch(void* const* d_in, const int* in_sizes, int n_in,
                              void* d_out, int out_size, void* d_ws, size_t ws_size,
                              hipStream_t stream) {
    const int*   seq = (const int*)  d_in[0];
    const float* emb = (const float*)d_in[1];
    const float* pes = (const float*)d_in[2];
    const float* wq  = (const float*)d_in[3];
    const float* bq  = (const float*)d_in[4];
    const float* wk  = (const float*)d_in[5];
    const float* bk  = (const float*)d_in[6];
    const float* wv  = (const float*)d_in[7];
    const float* bv  = (const float*)d_in[8];
    const float* wo  = (const float*)d_in[9];
    const float* bo  = (const float*)d_in[10];
    const float* ag  = (const float*)d_in[11];
    const float* ab  = (const float*)d_in[12];
    const float* am  = (const float*)d_in[13];
    const float* av  = (const float*)d_in[14];
    const float* w1  = (const float*)d_in[15];
    const float* b1  = (const float*)d_in[16];
    const float* w2  = (const float*)d_in[17];
    const float* b2  = (const float*)d_in[18];
    const float* fg  = (const float*)d_in[19];
    const float* fb  = (const float*)d_in[20];
    const float* fm  = (const float*)d_in[21];
    const float* fv  = (const float*)d_in[22];
    float* out = (float*)d_out;

    // workspace carve (~83 MB)
    char* p = (char*)d_ws;
    auto alloc = [&](size_t bytes) { char* q = p; p += (bytes + 255) & ~(size_t)255; return q; };
    float*  X     = (float*) alloc((size_t)M_ * D_ * 4);        // 16 MB
    bf16_t* Xb    = (bf16_t*)alloc((size_t)M_ * D_ * 2);        //  8 MB
    bf16_t* qkvb  = (bf16_t*)alloc((size_t)M_ * QKVN_ * 2);     //  2 MB
    float*  sc    = (float*) alloc((size_t)B_ * S_ * S_ * 4);   //  8 MB
    bf16_t* hdb   = (bf16_t*)alloc((size_t)M_ * DK_ * 2);       // .5 MB
    bf16_t* hb    = (bf16_t*)alloc((size_t)M_ * FF_ * 2);       // 32 MB
    bf16_t* w1t   = (bf16_t*)alloc((size_t)FF_ * D_ * 2);       //  8 MB
    bf16_t* w2t   = (bf16_t*)alloc((size_t)D_ * FF_ * 2);       //  8 MB
    bf16_t* wqkvt = (bf16_t*)alloc((size_t)QKVN_ * D_ * 2);     // .5 MB
    bf16_t* wot   = (bf16_t*)alloc((size_t)D_ * DK_ * 2);       // .125 MB
    float*  bqkv  = (float*) alloc(QKVN_ * 4);

    dim3 blk(16, 16);
    embed_kernel<<<M_ * D_ / 256, 256, 0, stream>>>(seq, emb, pes, X, Xb);

    for (int l = 0; l < L_; l++) {
        // --- fused weight prep (1 launch) ---
        prep_weights<<<8465, 256, 0, stream>>>(
            wq + (size_t)l * D_ * DK_, wk + (size_t)l * D_ * DK_, wv + (size_t)l * D_ * DK_,
            wo + (size_t)l * DK_ * D_, w1 + (size_t)l * D_ * FF_, w2 + (size_t)l * FF_ * D_,
            bq + l * DK_, bk + l * DK_, bv + l * DK_,
            wqkvt, wot, w1t, w2t, bqkv);

        // --- QKV: split-K=4, bf16 partials in d_out (8 MB) ---
        gemm_mfma3<2><<<dim3(QKVN_ / 128, M_ / 128, 4), 256, 0, stream>>>(
            Xb, wqkvt, nullptr, (bf16_t*)out, nullptr, nullptr, nullptr,
            nullptr, nullptr, nullptr, nullptr, QKVN_, D_, D_ / 4, (size_t)M_ * QKVN_);
        qkv_reduce<<<M_ * QKVN_ / 256, 256, 0, stream>>>((const bf16_t*)out, bqkv, qkvb);

        // --- attention ---
        score_kernel<<<dim3(S_ / 64, S_ / 64, B_), blk, 0, stream>>>(qkvb, sc, 0.125f);
        softmax_kernel<<<B_ * S_, 256, 0, stream>>>(sc);
        pv_kernel<<<dim3(4, S_ / 64, B_), blk, 0, stream>>>(sc, qkvb, (float*)out);
        pv_reduce<<<M_ * DK_ / 256, 256, 0, stream>>>((const float*)out, hdb);

        // --- output proj with fused BN1 epilogue ---
        gemm_mfma3<3><<<dim3(D_ / 128, M_ / 128, 1), 256, 0, stream>>>(
            hdb, wot, bo + l * D_, nullptr, X, X, Xb,
            ag + l * D_, ab + l * D_, am + l * D_, av + l * D_, D_, DK_, DK_, 0);

        // --- FFN1 (bf16 + relu) ---
        gemm_mfma3<1><<<dim3(FF_ / 128, M_ / 128, 1), 256, 0, stream>>>(
            Xb, w1t, b1 + l * FF_, hb, nullptr, nullptr, nullptr,
            nullptr, nullptr, nullptr, nullptr, FF_, D_, D_, 0);

        // --- FFN2: split-K=2, bf16 partials in d_out (16 MB) ---
        gemm_mfma3<2><<<dim3(D_ / 128, M_ / 128, 2), 256, 0, stream>>>(
            hb, w2t, nullptr, (bf16_t*)out, nullptr, nullptr, nullptr,
            nullptr, nullptr, nullptr, nullptr, D_, FF_, FF_ / 2, (size_t)M_ * D_);

        bn_residual2<<<M_ * D_ / 256, 256, 0, stream>>>(
            X, (const bf16_t*)out, b2 + l * D_,
            fg + l * D_, fb + l * D_, fm + l * D_, fv + l * D_, X, Xb);
        if (l == L_ - 1)
            hipMemcpyAsync(out, X, (size_t)M_ * D_ * 4, hipMemcpyDeviceToDevice, stream);
    }
}